// Round 5
// baseline (325.923 us; speedup 1.0000x reference)
//
#include <hip/hip_runtime.h>
#include <hip/hip_bf16.h>

constexpr int NN = 100000;   // nodes
constexpr int NE = 1600000;  // edges
constexpr int NF = 64;       // input features
constexpr int NH = 16;       // hidden

constexpr int NPB  = 64;                       // nodes per bucket (dst>>6 / dst&63)
constexpr int LB   = 6;                        // log2(NPB)
constexpr int NBKT = (NN + NPB - 1) / NPB;     // 1563 buckets
constexpr int CAP  = 1280;                     // per-bucket capacity (mean 1024, +8 sigma)
constexpr int CHUNK = 4096;                    // edges per block in bucket build
constexpr int NBLK_B = (NE + CHUNK - 1) / CHUNK; // 391

__device__ __forceinline__ float bf16_to_f32(unsigned short u) {
    return __uint_as_float(((unsigned int)u) << 16);
}
__device__ __forceinline__ unsigned short f32_to_bf16(float f) {
    __hip_bfloat16 hb = __float2bfloat16(f);   // RNE
    return *reinterpret_cast<unsigned short*>(&hb);
}

// Kernel 1: per node n: p[n,:] = bf16(x[n,:] @ Wl1) ; r[n,:] = x[n,:] @ Wr1
// p in bf16 -> 3.2 MB total, fits the 4 MB per-XCD L2 for the gather phase.
__global__ __launch_bounds__(256)
void k1_node_lin(const float* __restrict__ x,
                 const float* __restrict__ Wl1,
                 const float* __restrict__ Wr1,
                 unsigned short* __restrict__ p,
                 float* __restrict__ r)
{
    __shared__ float sW[2 * NF * NH];
    for (int i = threadIdx.x; i < NF * NH; i += 256) {
        sW[i]           = Wl1[i];
        sW[NF * NH + i] = Wr1[i];
    }
    __syncthreads();

    int n = blockIdx.x * 256 + threadIdx.x;
    if (n >= NN) return;

    float aL[NH], aR[NH];
#pragma unroll
    for (int j = 0; j < NH; ++j) { aL[j] = 0.f; aR[j] = 0.f; }

    const float4* xr = reinterpret_cast<const float4*>(x + (size_t)n * NF);
#pragma unroll
    for (int k4 = 0; k4 < NF / 4; ++k4) {
        float4 v = xr[k4];
        float xs[4] = {v.x, v.y, v.z, v.w};
#pragma unroll
        for (int t = 0; t < 4; ++t) {
            const float* wl = &sW[(k4 * 4 + t) * NH];
            const float* wr = &sW[NF * NH + (k4 * 4 + t) * NH];
#pragma unroll
            for (int j = 0; j < NH; ++j) {
                aL[j] = fmaf(xs[t], wl[j], aL[j]);
                aR[j] = fmaf(xs[t], wr[j], aR[j]);
            }
        }
    }

    // pack 16 bf16 = 32 B = two uint4 stores
    unsigned int pu[8];
#pragma unroll
    for (int j2 = 0; j2 < 8; ++j2)
        pu[j2] = (unsigned int)f32_to_bf16(aL[2*j2]) |
                 ((unsigned int)f32_to_bf16(aL[2*j2+1]) << 16);
    uint4* pp = reinterpret_cast<uint4*>(p + (size_t)n * NH);
    pp[0] = make_uint4(pu[0], pu[1], pu[2], pu[3]);
    pp[1] = make_uint4(pu[4], pu[5], pu[6], pu[7]);

    float4* rp = reinterpret_cast<float4*>(r + (size_t)n * NH);
#pragma unroll
    for (int j4 = 0; j4 < NH / 4; ++j4)
        rp[j4] = make_float4(aR[j4*4], aR[j4*4+1], aR[j4*4+2], aR[j4*4+3]);
}

// Bucket build: per-block LDS histogram -> one global reserve per
// (block,bucket) -> sequential tail appends (write-back ~= payload).
__global__ __launch_bounds__(256)
void k_bucket(const int* __restrict__ ei, const float* __restrict__ As,
              const float* __restrict__ ws,
              int* __restrict__ bcnt, unsigned int* __restrict__ bmem)
{
    __shared__ int lcnt[NBKT];
    __shared__ int lbase[NBKT];
    int tid = threadIdx.x;
    for (int i = tid; i < NBKT; i += 256) lcnt[i] = 0;
    __syncthreads();

    int base = blockIdx.x * CHUNK;
    float w0 = ws[0], w1 = ws[1];

#pragma unroll
    for (int j = 0; j < CHUNK / 256; ++j) {
        int e = base + j * 256 + tid;
        if (e < NE) {
            float ewm = w0 * As[e] + w1 * As[NE + e];
            if (ewm != 0.f)
                atomicAdd(&lcnt[ei[NE + e] >> LB], 1);
        }
    }
    __syncthreads();

    for (int i = tid; i < NBKT; i += 256) {
        int c = lcnt[i];
        lbase[i] = c ? atomicAdd(&bcnt[i], c) : 0;
    }
    __syncthreads();
    for (int i = tid; i < NBKT; i += 256) lcnt[i] = 0;
    __syncthreads();

#pragma unroll
    for (int j = 0; j < CHUNK / 256; ++j) {
        int e = base + j * 256 + tid;
        if (e < NE) {
            float ewm = w0 * As[e] + w1 * As[NE + e];
            if (ewm != 0.f) {
                int dst = ei[NE + e];
                int b   = dst >> LB;
                int rank = atomicAdd(&lcnt[b], 1);
                int slot = lbase[b] + rank;
                if (slot < CAP)
                    bmem[(size_t)b * CAP + slot] =
                        ((unsigned)ei[e] << LB) | (unsigned)(dst & (NPB - 1));
            }
        }
    }
}

// Layer-1 aggregation: one block per bucket; native ds_add_f32 accumulator;
// 16 lanes/edge gather one 32 B bf16 p-row (L2-resident). 8 edges in flight.
// Fused epilogue: h = relu(agg + r + bl1); q = h.Wl2; out = h.Wr2 + bl2.
__global__ __launch_bounds__(256)
void k_agg1(const int* __restrict__ bcnt, const unsigned int* __restrict__ bmem,
            const unsigned short* __restrict__ p, const float* __restrict__ r,
            const float* __restrict__ bl1, const float* __restrict__ Wl2,
            const float* __restrict__ bl2, const float* __restrict__ Wr2,
            float* __restrict__ q, float* __restrict__ out)
{
    __shared__ float sagg[NPB * NH];   // 4 KB
    int b = blockIdx.x;
    int tid = threadIdx.x;
    for (int i = tid; i < NPB * NH; i += 256) sagg[i] = 0.f;
    __syncthreads();

    int cnt = min(bcnt[b], CAP);
    int grp = tid >> 4, k = tid & 15;
    const unsigned int* bm = bmem + (size_t)b * CAP;

    int i = grp;
    for (; i + 7 * 16 < cnt; i += 8 * 16) {
        unsigned v[8];
#pragma unroll
        for (int u = 0; u < 8; ++u) v[u] = bm[i + u * 16];
        unsigned short pv[8];
#pragma unroll
        for (int u = 0; u < 8; ++u)
            pv[u] = p[(size_t)(v[u] >> LB) * NH + k];
#pragma unroll
        for (int u = 0; u < 8; ++u)
            unsafeAtomicAdd(&sagg[(v[u] & (NPB - 1)) * NH + k], bf16_to_f32(pv[u]));
    }
    for (; i < cnt; i += 16) {
        unsigned v = bm[i];
        unsafeAtomicAdd(&sagg[(v & (NPB - 1)) * NH + k],
                        bf16_to_f32(p[(size_t)(v >> LB) * NH + k]));
    }
    __syncthreads();

    int n0 = b * NPB;
    int nn = min(NPB, NN - n0);
    for (int item = tid; item < nn * NH; item += 256) {
        int l  = item >> 4;
        int kk = item & 15;
        float h = sagg[item] + r[(size_t)(n0 + l) * NH + kk] + bl1[kk];
        h = h > 0.f ? h : 0.f;
        float qv = h * Wl2[kk];
        float sv = h * Wr2[kk];
#pragma unroll
        for (int m = 8; m >= 1; m >>= 1) {
            qv += __shfl_xor(qv, m);
            sv += __shfl_xor(sv, m);
        }
        if (kk == 0) {
            q[n0 + l]   = qv;
            out[n0 + l] = sv + bl2[0];
        }
    }
}

// Layer-2 aggregation: native ds_add_f32 on LDS; q gathers are L2-resident.
__global__ __launch_bounds__(256)
void k_agg2(const int* __restrict__ bcnt, const unsigned int* __restrict__ bmem,
            const float* __restrict__ q, float* __restrict__ out)
{
    __shared__ float sq[NPB];
    int b = blockIdx.x, tid = threadIdx.x;
    if (tid < NPB) sq[tid] = 0.f;
    __syncthreads();

    int cnt = min(bcnt[b], CAP);
    const unsigned int* bm = bmem + (size_t)b * CAP;

    int i = tid;
    for (; i + 7 * 256 < cnt; i += 8 * 256) {
        unsigned v[8];
#pragma unroll
        for (int u = 0; u < 8; ++u) v[u] = bm[i + u * 256];
        float qv[8];
#pragma unroll
        for (int u = 0; u < 8; ++u) qv[u] = q[v[u] >> LB];
#pragma unroll
        for (int u = 0; u < 8; ++u)
            unsafeAtomicAdd(&sq[v[u] & (NPB - 1)], qv[u]);
    }
    for (; i < cnt; i += 256) {
        unsigned v = bm[i];
        unsafeAtomicAdd(&sq[v & (NPB - 1)], q[v >> LB]);
    }
    __syncthreads();

    int n0 = b * NPB;
    int nn = min(NPB, NN - n0);
    if (tid < nn) out[n0 + tid] += sq[tid];
}

extern "C" void kernel_launch(void* const* d_in, const int* in_sizes, int n_in,
                              void* d_out, int out_size, void* d_ws, size_t ws_size,
                              hipStream_t stream)
{
    const float* x   = (const float*)d_in[0];
    const int*   ei  = (const int*)  d_in[1];
    const float* As  = (const float*)d_in[2];
    const float* ws  = (const float*)d_in[3];
    const float* Wl1 = (const float*)d_in[4];
    const float* bl1 = (const float*)d_in[5];
    const float* Wr1 = (const float*)d_in[6];
    const float* Wl2 = (const float*)d_in[7];
    const float* bl2 = (const float*)d_in[8];
    const float* Wr2 = (const float*)d_in[9];
    float* out = (float*)d_out;

    // workspace (~18 MB)
    unsigned short* p    = (unsigned short*)d_ws;          // NN*NH bf16 (3.2 MB)
    float*          r    = (float*)(p + (size_t)NN * NH);  // NN*NH f32
    float*          q    = r + (size_t)NN * NH;            // NN
    int*            bcnt = (int*)(q + NN);                 // NBKT
    unsigned int*   bmem = (unsigned int*)(bcnt + NBKT);   // NBKT*CAP (8 MB)

    hipMemsetAsync(bcnt, 0, NBKT * sizeof(int), stream);

    k1_node_lin<<<(NN + 255) / 256, 256, 0, stream>>>(x, Wl1, Wr1, p, r);
    k_bucket<<<NBLK_B, 256, 0, stream>>>(ei, As, ws, bcnt, bmem);
    k_agg1<<<NBKT, 256, 0, stream>>>(bcnt, bmem, p, r, bl1, Wl2, bl2, Wr2, q, out);
    k_agg2<<<NBKT, 256, 0, stream>>>(bcnt, bmem, q, out);
}

// Round 6
// 185.719 us; speedup vs baseline: 1.7549x; 1.7549x over previous
//
#include <hip/hip_runtime.h>
#include <hip/hip_bf16.h>

constexpr int NN = 100000;   // nodes
constexpr int NE = 1600000;  // edges
constexpr int NF = 64;       // input features
constexpr int NH = 16;       // hidden

constexpr int NPB  = 64;                       // nodes per bucket (dst>>6 / dst&63)
constexpr int LB   = 6;                        // log2(NPB)
constexpr int NBKT = (NN + NPB - 1) / NPB;     // 1563 buckets
constexpr int CAP  = 1280;                     // per-bucket capacity (mean 1024, +8 sigma)
constexpr int CHUNK = 4096;                    // edges per block in bucket build
constexpr int NBLK_B = (NE + CHUNK - 1) / CHUNK; // 391

__device__ __forceinline__ float bf16_to_f32(unsigned short u) {
    return __uint_as_float(((unsigned int)u) << 16);
}
__device__ __forceinline__ unsigned short f32_to_bf16(float f) {
    __hip_bfloat16 hb = __float2bfloat16(f);   // RNE
    return *reinterpret_cast<unsigned short*>(&hb);
}

// Kernel 1: per node n: p[n,:] = bf16(x[n,:] @ Wl1) ; r[n,:] = x[n,:] @ Wr1
__global__ __launch_bounds__(256)
void k1_node_lin(const float* __restrict__ x,
                 const float* __restrict__ Wl1,
                 const float* __restrict__ Wr1,
                 unsigned short* __restrict__ p,
                 float* __restrict__ r)
{
    __shared__ float sW[2 * NF * NH];
    for (int i = threadIdx.x; i < NF * NH; i += 256) {
        sW[i]           = Wl1[i];
        sW[NF * NH + i] = Wr1[i];
    }
    __syncthreads();

    int n = blockIdx.x * 256 + threadIdx.x;
    if (n >= NN) return;

    float aL[NH], aR[NH];
#pragma unroll
    for (int j = 0; j < NH; ++j) { aL[j] = 0.f; aR[j] = 0.f; }

    const float4* xr = reinterpret_cast<const float4*>(x + (size_t)n * NF);
#pragma unroll
    for (int k4 = 0; k4 < NF / 4; ++k4) {
        float4 v = xr[k4];
        float xs[4] = {v.x, v.y, v.z, v.w};
#pragma unroll
        for (int t = 0; t < 4; ++t) {
            const float* wl = &sW[(k4 * 4 + t) * NH];
            const float* wr = &sW[NF * NH + (k4 * 4 + t) * NH];
#pragma unroll
            for (int j = 0; j < NH; ++j) {
                aL[j] = fmaf(xs[t], wl[j], aL[j]);
                aR[j] = fmaf(xs[t], wr[j], aR[j]);
            }
        }
    }

    unsigned int pu[8];
#pragma unroll
    for (int j2 = 0; j2 < 8; ++j2)
        pu[j2] = (unsigned int)f32_to_bf16(aL[2*j2]) |
                 ((unsigned int)f32_to_bf16(aL[2*j2+1]) << 16);
    uint4* pp = reinterpret_cast<uint4*>(p + (size_t)n * NH);
    pp[0] = make_uint4(pu[0], pu[1], pu[2], pu[3]);
    pp[1] = make_uint4(pu[4], pu[5], pu[6], pu[7]);

    float4* rp = reinterpret_cast<float4*>(r + (size_t)n * NH);
#pragma unroll
    for (int j4 = 0; j4 < NH / 4; ++j4)
        rp[j4] = make_float4(aR[j4*4], aR[j4*4+1], aR[j4*4+2], aR[j4*4+3]);
}

// Bucket build: stage chunk in LDS (single global read pass), LDS histogram,
// one global reserve per (block,bucket), sequential tail appends.
__global__ __launch_bounds__(256)
void k_bucket(const int* __restrict__ ei, const float* __restrict__ As,
              const float* __restrict__ ws,
              int* __restrict__ bcnt, unsigned int* __restrict__ bmem)
{
    __shared__ int lcnt[NBKT];                  // 6.25 KB
    __shared__ int lbase[NBKT];                 // 6.25 KB
    __shared__ unsigned int   sw[CHUNK];        // 16 KB packed (src<<6)|dl
    __shared__ unsigned short sbk[CHUNK];       // 8 KB bucket id (0xFFFF = dropped)
    int tid = threadIdx.x;
    for (int i = tid; i < NBKT; i += 256) lcnt[i] = 0;
    __syncthreads();

    int base = blockIdx.x * CHUNK;
    float w0 = ws[0], w1 = ws[1];

    // pass A: read globals once, stage + count
#pragma unroll
    for (int j = 0; j < CHUNK / 256; ++j) {
        int idx = j * 256 + tid;
        int e = base + idx;
        unsigned int w = 0;
        unsigned short bk = 0xFFFFu;
        if (e < NE) {
            float ewm = w0 * As[e] + w1 * As[NE + e];
            if (ewm != 0.f) {
                int dst = ei[NE + e];
                bk = (unsigned short)(dst >> LB);
                w  = ((unsigned)ei[e] << LB) | (unsigned)(dst & (NPB - 1));
                atomicAdd(&lcnt[dst >> LB], 1);
            }
        }
        sw[idx]  = w;
        sbk[idx] = bk;
    }
    __syncthreads();

    for (int i = tid; i < NBKT; i += 256) {
        int c = lcnt[i];
        lbase[i] = c ? atomicAdd(&bcnt[i], c) : 0;
    }
    __syncthreads();
    for (int i = tid; i < NBKT; i += 256) lcnt[i] = 0;
    __syncthreads();

    // pass B: place from LDS stage (no global re-read)
#pragma unroll
    for (int j = 0; j < CHUNK / 256; ++j) {
        int idx = j * 256 + tid;
        unsigned short bk = sbk[idx];
        if (bk != 0xFFFFu) {
            int rank = atomicAdd(&lcnt[bk], 1);
            int slot = lbase[bk] + rank;
            if (slot < CAP)
                bmem[(size_t)bk * CAP + slot] = sw[idx];
        }
    }
}

// Layer-1 aggregation, atomic-free: counting-sort bucket by dl in LDS, then
// each 16-lane group accumulates 4 nodes in registers. Sorted list written
// back to bmem (coalesced) + per-node offsets to gsoff for k_agg2.
// Fused epilogue: h = relu(acc + r + bl1); q = h.Wl2; out = h.Wr2 + bl2.
__global__ __launch_bounds__(256)
void k_agg1(const int* __restrict__ bcnt, unsigned int* __restrict__ bmem,
            const unsigned short* __restrict__ p, const float* __restrict__ r,
            const float* __restrict__ bl1, const float* __restrict__ Wl2,
            const float* __restrict__ bl2, const float* __restrict__ Wr2,
            float* __restrict__ q, float* __restrict__ out,
            int* __restrict__ gsoff)
{
    __shared__ unsigned int sbm[CAP];       // 5 KB raw
    __shared__ unsigned int ssorted[CAP];   // 5 KB sorted by dl
    __shared__ int hist[NPB];
    __shared__ int soff[NPB + 1];
    __shared__ int lrank[NPB];

    int b = blockIdx.x;
    int tid = threadIdx.x;
    if (tid < NPB) { hist[tid] = 0; lrank[tid] = 0; }
    __syncthreads();

    int cnt = min(bcnt[b], CAP);

    // phase 1: stage + histogram (int LDS atomics, 64 counters)
    for (int i = tid; i < cnt; i += 256) {
        unsigned int w = bmem[(size_t)b * CAP + i];
        sbm[i] = w;
        atomicAdd(&hist[w & (NPB - 1)], 1);
    }
    __syncthreads();

    // phase 2: exclusive scan of 64 counters (wave 0)
    if (tid < NPB) {
        int v = hist[tid];
        int inc = v;
#pragma unroll
        for (int off = 1; off < NPB; off <<= 1) {
            int u = __shfl_up(inc, off);
            if (tid >= off) inc += u;
        }
        soff[tid + 1] = inc;
        if (tid == 0) soff[0] = 0;
    }
    __syncthreads();

    // phase 3: rank-scatter into ssorted
    for (int i = tid; i < cnt; i += 256) {
        unsigned int w = sbm[i];
        int dl = w & (NPB - 1);
        int pos = soff[dl] + atomicAdd(&lrank[dl], 1);
        ssorted[pos] = w;
    }
    __syncthreads();

    // phase 4: export sorted list (coalesced, overwrites bmem) + offsets
    for (int i = tid; i < cnt; i += 256)
        bmem[(size_t)b * CAP + i] = ssorted[i];
    if (tid < NPB + 1)
        gsoff[(size_t)b * (NPB + 1) + tid] = soff[tid];

    // phase 5: register accumulation — group g owns nodes 4g..4g+3, lane k owns feature k
    int g = tid >> 4, k = tid & 15;
    int n0 = b * NPB;
#pragma unroll
    for (int jj = 0; jj < 4; ++jj) {
        int nl = g * 4 + jj;
        int s = soff[nl], e = soff[nl + 1];
        float a = 0.f;
        int i = s;
        for (; i + 3 < e; i += 4) {
            unsigned w0 = ssorted[i], w1 = ssorted[i+1], w2 = ssorted[i+2], w3 = ssorted[i+3];
            float v0 = bf16_to_f32(p[(size_t)(w0 >> LB) * NH + k]);
            float v1 = bf16_to_f32(p[(size_t)(w1 >> LB) * NH + k]);
            float v2 = bf16_to_f32(p[(size_t)(w2 >> LB) * NH + k]);
            float v3 = bf16_to_f32(p[(size_t)(w3 >> LB) * NH + k]);
            a += (v0 + v1) + (v2 + v3);
        }
        for (; i < e; ++i)
            a += bf16_to_f32(p[(size_t)(ssorted[i] >> LB) * NH + k]);

        int n = n0 + nl;
        if (n < NN) {
            float h = a + r[(size_t)n * NH + k] + bl1[k];
            h = h > 0.f ? h : 0.f;
            float qv = h * Wl2[k];
            float sv = h * Wr2[k];
#pragma unroll
            for (int m = 8; m >= 1; m >>= 1) {   // xor <16 stays in the group
                qv += __shfl_xor(qv, m);
                sv += __shfl_xor(sv, m);
            }
            if (k == 0) {
                q[n]   = qv;
                out[n] = sv + bl2[0];
            }
        }
    }
}

// Layer-2 aggregation, atomic-free: one thread per node scans its sorted
// segment (sequential global reads) and gathers q[src] (L2-resident).
__global__ __launch_bounds__(256)
void k_agg2(const int* __restrict__ gsoff, const unsigned int* __restrict__ bmem,
            const float* __restrict__ q, float* __restrict__ out)
{
    int n = blockIdx.x * 256 + threadIdx.x;
    if (n >= NN) return;
    int b  = n >> LB;
    int dl = n & (NPB - 1);
    int s = gsoff[(size_t)b * (NPB + 1) + dl];
    int e = gsoff[(size_t)b * (NPB + 1) + dl + 1];
    const unsigned int* bm = bmem + (size_t)b * CAP;

    float a = 0.f;
    int i = s;
    for (; i + 3 < e; i += 4) {
        unsigned w0 = bm[i], w1 = bm[i+1], w2 = bm[i+2], w3 = bm[i+3];
        a += (q[w0 >> LB] + q[w1 >> LB]) + (q[w2 >> LB] + q[w3 >> LB]);
    }
    for (; i < e; ++i)
        a += q[bm[i] >> LB];
    out[n] += a;
}

extern "C" void kernel_launch(void* const* d_in, const int* in_sizes, int n_in,
                              void* d_out, int out_size, void* d_ws, size_t ws_size,
                              hipStream_t stream)
{
    const float* x   = (const float*)d_in[0];
    const int*   ei  = (const int*)  d_in[1];
    const float* As  = (const float*)d_in[2];
    const float* ws  = (const float*)d_in[3];
    const float* Wl1 = (const float*)d_in[4];
    const float* bl1 = (const float*)d_in[5];
    const float* Wr1 = (const float*)d_in[6];
    const float* Wl2 = (const float*)d_in[7];
    const float* bl2 = (const float*)d_in[8];
    const float* Wr2 = (const float*)d_in[9];
    float* out = (float*)d_out;

    // workspace (~18.6 MB)
    unsigned short* p     = (unsigned short*)d_ws;           // NN*NH bf16 (3.2 MB)
    float*          r     = (float*)(p + (size_t)NN * NH);   // NN*NH f32 (6.4 MB)
    float*          q     = r + (size_t)NN * NH;             // NN
    int*            bcnt  = (int*)(q + NN);                  // NBKT
    int*            gsoff = bcnt + NBKT;                     // NBKT*(NPB+1) (0.4 MB)
    unsigned int*   bmem  = (unsigned int*)(gsoff + (size_t)NBKT * (NPB + 1)); // 8 MB

    hipMemsetAsync(bcnt, 0, NBKT * sizeof(int), stream);

    k1_node_lin<<<(NN + 255) / 256, 256, 0, stream>>>(x, Wl1, Wr1, p, r);
    k_bucket<<<NBLK_B, 256, 0, stream>>>(ei, As, ws, bcnt, bmem);
    k_agg1<<<NBKT, 256, 0, stream>>>(bcnt, bmem, p, r, bl1, Wl2, bl2, Wr2, q, out, gsoff);
    k_agg2<<<(NN + 255) / 256, 256, 0, stream>>>(gsoff, bmem, q, out);
}

// Round 7
// 181.026 us; speedup vs baseline: 1.8004x; 1.0259x over previous
//
#include <hip/hip_runtime.h>
#include <hip/hip_bf16.h>

constexpr int NN = 100000;   // nodes
constexpr int NE = 1600000;  // edges
constexpr int NF = 64;       // input features
constexpr int NH = 16;       // hidden

constexpr int NPB  = 128;                      // nodes per bucket (dst>>7 / dst&127)
constexpr int LB   = 7;                        // log2(NPB)
constexpr int NBKT = (NN + NPB - 1) / NPB;     // 782 buckets
constexpr int CAP  = 2560;                     // per-bucket capacity (mean 2048, +11 sigma)
constexpr int CHUNK = 8192;                    // edges per block in bucket build
constexpr int TB_B  = 512;                     // k_bucket block size
constexpr int NBLK_B = (NE + CHUNK - 1) / CHUNK; // 196

__device__ __forceinline__ float bf16_to_f32(unsigned short u) {
    return __uint_as_float(((unsigned int)u) << 16);
}
__device__ __forceinline__ unsigned short f32_to_bf16(float f) {
    __hip_bfloat16 hb = __float2bfloat16(f);   // RNE
    return *reinterpret_cast<unsigned short*>(&hb);
}

// Kernel 1: per node n: p[n,:] = bf16(x[n,:] @ Wl1) ; r[n,:] = x[n,:] @ Wr1
__global__ __launch_bounds__(256)
void k1_node_lin(const float* __restrict__ x,
                 const float* __restrict__ Wl1,
                 const float* __restrict__ Wr1,
                 unsigned short* __restrict__ p,
                 float* __restrict__ r)
{
    __shared__ float sW[2 * NF * NH];
    for (int i = threadIdx.x; i < NF * NH; i += 256) {
        sW[i]           = Wl1[i];
        sW[NF * NH + i] = Wr1[i];
    }
    __syncthreads();

    int n = blockIdx.x * 256 + threadIdx.x;
    if (n >= NN) return;

    float aL[NH], aR[NH];
#pragma unroll
    for (int j = 0; j < NH; ++j) { aL[j] = 0.f; aR[j] = 0.f; }

    const float4* xr = reinterpret_cast<const float4*>(x + (size_t)n * NF);
#pragma unroll
    for (int k4 = 0; k4 < NF / 4; ++k4) {
        float4 v = xr[k4];
        float xs[4] = {v.x, v.y, v.z, v.w};
#pragma unroll
        for (int t = 0; t < 4; ++t) {
            const float* wl = &sW[(k4 * 4 + t) * NH];
            const float* wr = &sW[NF * NH + (k4 * 4 + t) * NH];
#pragma unroll
            for (int j = 0; j < NH; ++j) {
                aL[j] = fmaf(xs[t], wl[j], aL[j]);
                aR[j] = fmaf(xs[t], wr[j], aR[j]);
            }
        }
    }

    unsigned int pu[8];
#pragma unroll
    for (int j2 = 0; j2 < 8; ++j2)
        pu[j2] = (unsigned int)f32_to_bf16(aL[2*j2]) |
                 ((unsigned int)f32_to_bf16(aL[2*j2+1]) << 16);
    uint4* pp = reinterpret_cast<uint4*>(p + (size_t)n * NH);
    pp[0] = make_uint4(pu[0], pu[1], pu[2], pu[3]);
    pp[1] = make_uint4(pu[4], pu[5], pu[6], pu[7]);

    float4* rp = reinterpret_cast<float4*>(r + (size_t)n * NH);
#pragma unroll
    for (int j4 = 0; j4 < NH / 4; ++j4)
        rp[j4] = make_float4(aR[j4*4], aR[j4*4+1], aR[j4*4+2], aR[j4*4+3]);
}

// Bucket build: single atomic pass (the count atomic IS the rank), LDS stage,
// one global reserve per (block,bucket), then sequential tail appends.
// Fragments avg 10.5 words (42 B) with CHUNK=8192/NBKT=782.
__global__ __launch_bounds__(TB_B)
void k_bucket(const int* __restrict__ ei, const float* __restrict__ As,
              const float* __restrict__ ws,
              int* __restrict__ bcnt, unsigned int* __restrict__ bmem)
{
    __shared__ unsigned int sw[CHUNK];    // 32 KB packed (src<<7)|dl
    __shared__ unsigned int srk[CHUNK];   // 32 KB (bk<<13)|rank, ~0 = dropped
    __shared__ int lcnt[NBKT];            // 3.1 KB
    __shared__ int lbase[NBKT];           // 3.1 KB
    int tid = threadIdx.x;
    for (int i = tid; i < NBKT; i += TB_B) lcnt[i] = 0;
    __syncthreads();

    int base = blockIdx.x * CHUNK;
    float w0 = ws[0], w1 = ws[1];

    // pass A: read globals once; count atomic doubles as within-block rank
#pragma unroll
    for (int j = 0; j < CHUNK / TB_B; ++j) {
        int idx = j * TB_B + tid;
        int e = base + idx;
        unsigned int w = 0, rk = 0xFFFFFFFFu;
        if (e < NE) {
            float ewm = w0 * As[e] + w1 * As[NE + e];
            if (ewm != 0.f) {
                int dst = ei[NE + e];
                int bk  = dst >> LB;
                w  = ((unsigned)ei[e] << LB) | (unsigned)(dst & (NPB - 1));
                int rank = atomicAdd(&lcnt[bk], 1);      // rank < 8192 fits 13 bits
                rk = ((unsigned)bk << 13) | (unsigned)rank;
            }
        }
        sw[idx]  = w;
        srk[idx] = rk;
    }
    __syncthreads();

    // reserve contiguous ranges (one global atomic per nonzero bucket)
    for (int i = tid; i < NBKT; i += TB_B) {
        int c = lcnt[i];
        lbase[i] = c ? atomicAdd(&bcnt[i], c) : 0;
    }
    __syncthreads();

    // pass B: place from LDS stage using stored ranks (no atomics)
#pragma unroll
    for (int j = 0; j < CHUNK / TB_B; ++j) {
        int idx = j * TB_B + tid;
        unsigned int rk = srk[idx];
        if (rk != 0xFFFFFFFFu) {
            int bk   = rk >> 13;
            int rank = rk & 0x1FFF;
            int slot = lbase[bk] + rank;
            if (slot < CAP)
                bmem[(size_t)bk * CAP + slot] = sw[idx];
        }
    }
}

// Layer-1 aggregation, atomic-light: counting-sort by dl (hist atomic returns
// the rank; no second atomic pass), then 16-lane groups accumulate 8 nodes
// each in registers. Sorted list + offsets exported for k_agg2.
// Fused epilogue: h = relu(acc + r + bl1); q = h.Wl2; out = h.Wr2 + bl2.
__global__ __launch_bounds__(256)
void k_agg1(const int* __restrict__ bcnt, unsigned int* __restrict__ bmem,
            const unsigned short* __restrict__ p, const float* __restrict__ r,
            const float* __restrict__ bl1, const float* __restrict__ Wl2,
            const float* __restrict__ bl2, const float* __restrict__ Wr2,
            float* __restrict__ q, float* __restrict__ out,
            int* __restrict__ gsoff)
{
    __shared__ unsigned int sbm[CAP];       // 10 KB raw
    __shared__ unsigned int ssorted[CAP];   // 10 KB sorted by dl
    __shared__ int hist[NPB];
    __shared__ int scan[NPB];
    __shared__ int soff[NPB + 1];

    int b = blockIdx.x;
    int tid = threadIdx.x;
    if (tid < NPB) hist[tid] = 0;
    __syncthreads();

    int cnt = min(bcnt[b], CAP);

    // phase 1: stage + histogram; the atomic's return value is the rank
    int rk[CAP / 256];                      // 10 slots
#pragma unroll
    for (int j = 0; j < CAP / 256; ++j) {
        int i = j * 256 + tid;
        if (i < cnt) {
            unsigned int w = bmem[(size_t)b * CAP + i];
            sbm[i] = w;
            rk[j] = atomicAdd(&hist[w & (NPB - 1)], 1);
        }
    }
    __syncthreads();

    // phase 2: exclusive scan of 128 counters (Hillis-Steele in LDS)
    if (tid < NPB) scan[tid] = hist[tid];
    __syncthreads();
    for (int off = 1; off < NPB; off <<= 1) {
        int u = (tid < NPB && tid >= off) ? scan[tid - off] : 0;
        __syncthreads();
        if (tid < NPB) scan[tid] += u;
        __syncthreads();
    }
    if (tid < NPB) soff[tid + 1] = scan[tid];
    if (tid == 0) soff[0] = 0;
    __syncthreads();

    // phase 3: rank-scatter into ssorted (no atomics — ranks precomputed)
#pragma unroll
    for (int j = 0; j < CAP / 256; ++j) {
        int i = j * 256 + tid;
        if (i < cnt) {
            unsigned int w = sbm[i];
            ssorted[soff[w & (NPB - 1)] + rk[j]] = w;
        }
    }
    __syncthreads();

    // phase 4: export sorted list (coalesced, overwrites bmem) + offsets
    for (int i = tid; i < cnt; i += 256)
        bmem[(size_t)b * CAP + i] = ssorted[i];
    if (tid < NPB + 1)
        gsoff[(size_t)b * (NPB + 1) + tid] = soff[tid];

    // phase 5: register accumulation — group g owns nodes 8g..8g+7, lane k owns feature k
    int g = tid >> 4, k = tid & 15;
    int n0 = b * NPB;
#pragma unroll
    for (int jj = 0; jj < 8; ++jj) {
        int nl = g * 8 + jj;
        int s = soff[nl], e = soff[nl + 1];
        float a = 0.f;
        int i = s;
        for (; i + 3 < e; i += 4) {
            unsigned w0 = ssorted[i], w1 = ssorted[i+1], w2 = ssorted[i+2], w3 = ssorted[i+3];
            float v0 = bf16_to_f32(p[(size_t)(w0 >> LB) * NH + k]);
            float v1 = bf16_to_f32(p[(size_t)(w1 >> LB) * NH + k]);
            float v2 = bf16_to_f32(p[(size_t)(w2 >> LB) * NH + k]);
            float v3 = bf16_to_f32(p[(size_t)(w3 >> LB) * NH + k]);
            a += (v0 + v1) + (v2 + v3);
        }
        for (; i < e; ++i)
            a += bf16_to_f32(p[(size_t)(ssorted[i] >> LB) * NH + k]);

        int n = n0 + nl;
        if (n < NN) {
            float h = a + r[(size_t)n * NH + k] + bl1[k];
            h = h > 0.f ? h : 0.f;
            float qv = h * Wl2[k];
            float sv = h * Wr2[k];
#pragma unroll
            for (int m = 8; m >= 1; m >>= 1) {   // xor <16 stays in the group
                qv += __shfl_xor(qv, m);
                sv += __shfl_xor(sv, m);
            }
            if (k == 0) {
                q[n]   = qv;
                out[n] = sv + bl2[0];
            }
        }
    }
}

// Layer-2 aggregation, atomic-free: one thread per node scans its sorted
// segment (sequential reads) and gathers q[src] (L2-resident, 400 KB).
__global__ __launch_bounds__(256)
void k_agg2(const int* __restrict__ gsoff, const unsigned int* __restrict__ bmem,
            const float* __restrict__ q, float* __restrict__ out)
{
    int n = blockIdx.x * 256 + threadIdx.x;
    if (n >= NN) return;
    int b  = n >> LB;
    int dl = n & (NPB - 1);
    int s = gsoff[(size_t)b * (NPB + 1) + dl];
    int e = gsoff[(size_t)b * (NPB + 1) + dl + 1];
    const unsigned int* bm = bmem + (size_t)b * CAP;

    float a = 0.f;
    int i = s;
    for (; i + 3 < e; i += 4) {
        unsigned w0 = bm[i], w1 = bm[i+1], w2 = bm[i+2], w3 = bm[i+3];
        a += (q[w0 >> LB] + q[w1 >> LB]) + (q[w2 >> LB] + q[w3 >> LB]);
    }
    for (; i < e; ++i)
        a += q[bm[i] >> LB];
    out[n] += a;
}

extern "C" void kernel_launch(void* const* d_in, const int* in_sizes, int n_in,
                              void* d_out, int out_size, void* d_ws, size_t ws_size,
                              hipStream_t stream)
{
    const float* x   = (const float*)d_in[0];
    const int*   ei  = (const int*)  d_in[1];
    const float* As  = (const float*)d_in[2];
    const float* ws  = (const float*)d_in[3];
    const float* Wl1 = (const float*)d_in[4];
    const float* bl1 = (const float*)d_in[5];
    const float* Wr1 = (const float*)d_in[6];
    const float* Wl2 = (const float*)d_in[7];
    const float* bl2 = (const float*)d_in[8];
    const float* Wr2 = (const float*)d_in[9];
    float* out = (float*)d_out;

    // workspace (~18.5 MB)
    unsigned short* p     = (unsigned short*)d_ws;           // NN*NH bf16 (3.2 MB)
    float*          r     = (float*)(p + (size_t)NN * NH);   // NN*NH f32 (6.4 MB)
    float*          q     = r + (size_t)NN * NH;             // NN
    int*            bcnt  = (int*)(q + NN);                  // NBKT
    int*            gsoff = bcnt + NBKT;                     // NBKT*(NPB+1) (0.4 MB)
    unsigned int*   bmem  = (unsigned int*)(gsoff + (size_t)NBKT * (NPB + 1)); // 8 MB

    hipMemsetAsync(bcnt, 0, NBKT * sizeof(int), stream);

    k1_node_lin<<<(NN + 255) / 256, 256, 0, stream>>>(x, Wl1, Wr1, p, r);
    k_bucket<<<NBLK_B, TB_B, 0, stream>>>(ei, As, ws, bcnt, bmem);
    k_agg1<<<NBKT, 256, 0, stream>>>(bcnt, bmem, p, r, bl1, Wl2, bl2, Wr2, q, out, gsoff);
    k_agg2<<<(NN + 255) / 256, 256, 0, stream>>>(gsoff, bmem, q, out);
}

// Round 8
// 178.738 us; speedup vs baseline: 1.8235x; 1.0128x over previous
//
#include <hip/hip_runtime.h>
#include <hip/hip_bf16.h>

constexpr int NN = 100000;   // nodes
constexpr int NE = 1600000;  // edges
constexpr int NF = 64;       // input features
constexpr int NH = 16;       // hidden

constexpr int NPB  = 128;                      // nodes per bucket (dst>>7 / dst&127)
constexpr int LB   = 7;                        // log2(NPB)
constexpr int NBKT = (NN + NPB - 1) / NPB;     // 782 buckets
constexpr int CAP  = 2560;                     // per-bucket capacity (mean 2048, +11 sigma)
constexpr int CHUNK = 4096;                    // edges per bucket-role block
constexpr int NBLK_B  = (NE + CHUNK - 1) / CHUNK;  // 391 bucket-role blocks
constexpr int NBLK_K1 = (NN + 255) / 256;          // 391 gemm-role blocks

// shared-memory overlay: max(k1 weights 8 KB, bucket {srk 8 KB + 2*NBKT ints})
constexpr int SMEM_BYTES = (CHUNK * 2 + 2 * NBKT * 4) > (2 * NF * NH * 4)
                         ? (CHUNK * 2 + 2 * NBKT * 4) : (2 * NF * NH * 4);

__device__ __forceinline__ float bf16_to_f32(unsigned short u) {
    return __uint_as_float(((unsigned int)u) << 16);
}
__device__ __forceinline__ unsigned short f32_to_bf16(float f) {
    __hip_bfloat16 hb = __float2bfloat16(f);   // RNE
    return *reinterpret_cast<unsigned short*>(&hb);
}

// Fused front-end. Even blocks: p = bf16(x@Wl1), r = x@Wr1 (BW/VALU-bound).
// Odd blocks: bucket build (LDS-atomic-bound). The two roles co-schedule on
// each CU, overlapping memory and LDS pipes (sum -> max).
__global__ __launch_bounds__(256)
void k_fused(const float* __restrict__ x,
             const float* __restrict__ Wl1,
             const float* __restrict__ Wr1,
             unsigned short* __restrict__ p,
             float* __restrict__ r,
             const int* __restrict__ ei, const float* __restrict__ As,
             const float* __restrict__ ws,
             int* __restrict__ bcnt, unsigned int* __restrict__ bmem)
{
    __shared__ __align__(16) char smem[SMEM_BYTES];
    int role = blockIdx.x & 1;
    int rb   = blockIdx.x >> 1;
    int tid  = threadIdx.x;

    if (role == 0) {
        // ---- GEMM role: nodes rb*256 .. rb*256+255 ----
        float* sW = (float*)smem;                       // Wl1 | Wr1 row-major
        for (int i = tid; i < NF * NH; i += 256) {
            sW[i]           = Wl1[i];
            sW[NF * NH + i] = Wr1[i];
        }
        __syncthreads();

        int n = rb * 256 + tid;
        if (n >= NN) return;

        float aL[NH], aR[NH];
#pragma unroll
        for (int j = 0; j < NH; ++j) { aL[j] = 0.f; aR[j] = 0.f; }

        const float4* xr = reinterpret_cast<const float4*>(x + (size_t)n * NF);
#pragma unroll
        for (int k4 = 0; k4 < NF / 4; ++k4) {
            float4 v = xr[k4];
            float xs[4] = {v.x, v.y, v.z, v.w};
#pragma unroll
            for (int t = 0; t < 4; ++t) {
                const float* wl = &sW[(k4 * 4 + t) * NH];
                const float* wr = &sW[NF * NH + (k4 * 4 + t) * NH];
#pragma unroll
                for (int j = 0; j < NH; ++j) {
                    aL[j] = fmaf(xs[t], wl[j], aL[j]);
                    aR[j] = fmaf(xs[t], wr[j], aR[j]);
                }
            }
        }

        unsigned int pu[8];
#pragma unroll
        for (int j2 = 0; j2 < 8; ++j2)
            pu[j2] = (unsigned int)f32_to_bf16(aL[2*j2]) |
                     ((unsigned int)f32_to_bf16(aL[2*j2+1]) << 16);
        uint4* pp = reinterpret_cast<uint4*>(p + (size_t)n * NH);
        pp[0] = make_uint4(pu[0], pu[1], pu[2], pu[3]);
        pp[1] = make_uint4(pu[4], pu[5], pu[6], pu[7]);

        float4* rp = reinterpret_cast<float4*>(r + (size_t)n * NH);
#pragma unroll
        for (int j4 = 0; j4 < NH / 4; ++j4)
            rp[j4] = make_float4(aR[j4*4], aR[j4*4+1], aR[j4*4+2], aR[j4*4+3]);
    } else {
        // ---- Bucket role: edges rb*CHUNK .. +CHUNK ----
        unsigned short* srk = (unsigned short*)smem;            // CHUNK ranks
        int* lcnt  = (int*)(smem + CHUNK * 2);                  // NBKT
        int* lbase = lcnt + NBKT;                               // NBKT

        for (int i = tid; i < NBKT; i += 256) lcnt[i] = 0;
        __syncthreads();

        int base = rb * CHUNK;
        float w0 = ws[0], w1 = ws[1];

        // pass A: mask + count; the count atomic's return IS the rank (<4096)
#pragma unroll
        for (int j = 0; j < CHUNK / 256; ++j) {
            int idx = j * 256 + tid;
            int e = base + idx;
            unsigned short rk = 0xFFFFu;
            if (e < NE) {
                float ewm = w0 * As[e] + w1 * As[NE + e];
                if (ewm != 0.f)
                    rk = (unsigned short)atomicAdd(&lcnt[ei[NE + e] >> LB], 1);
            }
            srk[idx] = rk;
        }
        __syncthreads();

        // reserve contiguous ranges (one global atomic per nonzero bucket)
        for (int i = tid; i < NBKT; i += 256) {
            int c = lcnt[i];
            lbase[i] = c ? atomicAdd(&bcnt[i], c) : 0;
        }
        __syncthreads();

        // pass B: re-read ei (L2-hot from pass A), place with stored rank
#pragma unroll
        for (int j = 0; j < CHUNK / 256; ++j) {
            int idx = j * 256 + tid;
            unsigned short rk = srk[idx];
            if (rk != 0xFFFFu) {
                int e   = base + idx;
                int dst = ei[NE + e];
                int bk  = dst >> LB;
                int slot = lbase[bk] + rk;
                if (slot < CAP)
                    bmem[(size_t)bk * CAP + slot] =
                        ((unsigned)ei[e] << LB) | (unsigned)(dst & (NPB - 1));
            }
        }
    }
}

// Layer-1 aggregation, atomic-light: counting-sort by dl (hist atomic returns
// the rank), then 16-lane groups accumulate 8 nodes each in registers.
// Sorted list + offsets exported for k_agg2.
// Fused epilogue: h = relu(acc + r + bl1); q = h.Wl2; out = h.Wr2 + bl2.
__global__ __launch_bounds__(256)
void k_agg1(const int* __restrict__ bcnt, unsigned int* __restrict__ bmem,
            const unsigned short* __restrict__ p, const float* __restrict__ r,
            const float* __restrict__ bl1, const float* __restrict__ Wl2,
            const float* __restrict__ bl2, const float* __restrict__ Wr2,
            float* __restrict__ q, float* __restrict__ out,
            int* __restrict__ gsoff)
{
    __shared__ unsigned int sbm[CAP];       // 10 KB raw
    __shared__ unsigned int ssorted[CAP];   // 10 KB sorted by dl
    __shared__ int hist[NPB];
    __shared__ int scan[NPB];
    __shared__ int soff[NPB + 1];

    int b = blockIdx.x;
    int tid = threadIdx.x;
    if (tid < NPB) hist[tid] = 0;
    __syncthreads();

    int cnt = min(bcnt[b], CAP);

    // phase 1: stage + histogram; the atomic's return value is the rank
    int rk[CAP / 256];                      // 10 slots
#pragma unroll
    for (int j = 0; j < CAP / 256; ++j) {
        int i = j * 256 + tid;
        if (i < cnt) {
            unsigned int w = bmem[(size_t)b * CAP + i];
            sbm[i] = w;
            rk[j] = atomicAdd(&hist[w & (NPB - 1)], 1);
        }
    }
    __syncthreads();

    // phase 2: exclusive scan of 128 counters
    if (tid < NPB) scan[tid] = hist[tid];
    __syncthreads();
    for (int off = 1; off < NPB; off <<= 1) {
        int u = (tid < NPB && tid >= off) ? scan[tid - off] : 0;
        __syncthreads();
        if (tid < NPB) scan[tid] += u;
        __syncthreads();
    }
    if (tid < NPB) soff[tid + 1] = scan[tid];
    if (tid == 0) soff[0] = 0;
    __syncthreads();

    // phase 3: rank-scatter into ssorted (ranks precomputed)
#pragma unroll
    for (int j = 0; j < CAP / 256; ++j) {
        int i = j * 256 + tid;
        if (i < cnt) {
            unsigned int w = sbm[i];
            ssorted[soff[w & (NPB - 1)] + rk[j]] = w;
        }
    }
    __syncthreads();

    // phase 4: export sorted list (coalesced, overwrites bmem) + offsets
    for (int i = tid; i < cnt; i += 256)
        bmem[(size_t)b * CAP + i] = ssorted[i];
    if (tid < NPB + 1)
        gsoff[(size_t)b * (NPB + 1) + tid] = soff[tid];

    // phase 5: register accumulation — group g owns nodes 8g..8g+7, lane k feature k
    int g = tid >> 4, k = tid & 15;
    int n0 = b * NPB;
#pragma unroll
    for (int jj = 0; jj < 8; ++jj) {
        int nl = g * 8 + jj;
        int s = soff[nl], e = soff[nl + 1];
        float a = 0.f;
        int i = s;
        for (; i + 3 < e; i += 4) {
            unsigned w0 = ssorted[i], w1 = ssorted[i+1], w2 = ssorted[i+2], w3 = ssorted[i+3];
            float v0 = bf16_to_f32(p[(size_t)(w0 >> LB) * NH + k]);
            float v1 = bf16_to_f32(p[(size_t)(w1 >> LB) * NH + k]);
            float v2 = bf16_to_f32(p[(size_t)(w2 >> LB) * NH + k]);
            float v3 = bf16_to_f32(p[(size_t)(w3 >> LB) * NH + k]);
            a += (v0 + v1) + (v2 + v3);
        }
        for (; i < e; ++i)
            a += bf16_to_f32(p[(size_t)(ssorted[i] >> LB) * NH + k]);

        int n = n0 + nl;
        if (n < NN) {
            float h = a + r[(size_t)n * NH + k] + bl1[k];
            h = h > 0.f ? h : 0.f;
            float qv = h * Wl2[k];
            float sv = h * Wr2[k];
#pragma unroll
            for (int m = 8; m >= 1; m >>= 1) {   // xor <16 stays in the group
                qv += __shfl_xor(qv, m);
                sv += __shfl_xor(sv, m);
            }
            if (k == 0) {
                q[n]   = qv;
                out[n] = sv + bl2[0];
            }
        }
    }
}

// Layer-2 aggregation, atomic-free: one thread per node scans its sorted
// segment (sequential reads) and gathers q[src] (L2-resident, 400 KB).
__global__ __launch_bounds__(256)
void k_agg2(const int* __restrict__ gsoff, const unsigned int* __restrict__ bmem,
            const float* __restrict__ q, float* __restrict__ out)
{
    int n = blockIdx.x * 256 + threadIdx.x;
    if (n >= NN) return;
    int b  = n >> LB;
    int dl = n & (NPB - 1);
    int s = gsoff[(size_t)b * (NPB + 1) + dl];
    int e = gsoff[(size_t)b * (NPB + 1) + dl + 1];
    const unsigned int* bm = bmem + (size_t)b * CAP;

    float a = 0.f;
    int i = s;
    for (; i + 3 < e; i += 4) {
        unsigned w0 = bm[i], w1 = bm[i+1], w2 = bm[i+2], w3 = bm[i+3];
        a += (q[w0 >> LB] + q[w1 >> LB]) + (q[w2 >> LB] + q[w3 >> LB]);
    }
    for (; i < e; ++i)
        a += q[bm[i] >> LB];
    out[n] += a;
}

extern "C" void kernel_launch(void* const* d_in, const int* in_sizes, int n_in,
                              void* d_out, int out_size, void* d_ws, size_t ws_size,
                              hipStream_t stream)
{
    const float* x   = (const float*)d_in[0];
    const int*   ei  = (const int*)  d_in[1];
    const float* As  = (const float*)d_in[2];
    const float* ws  = (const float*)d_in[3];
    const float* Wl1 = (const float*)d_in[4];
    const float* bl1 = (const float*)d_in[5];
    const float* Wr1 = (const float*)d_in[6];
    const float* Wl2 = (const float*)d_in[7];
    const float* bl2 = (const float*)d_in[8];
    const float* Wr2 = (const float*)d_in[9];
    float* out = (float*)d_out;

    // workspace (~18.5 MB)
    unsigned short* p     = (unsigned short*)d_ws;           // NN*NH bf16 (3.2 MB)
    float*          r     = (float*)(p + (size_t)NN * NH);   // NN*NH f32 (6.4 MB)
    float*          q     = r + (size_t)NN * NH;             // NN
    int*            bcnt  = (int*)(q + NN);                  // NBKT
    int*            gsoff = bcnt + NBKT;                     // NBKT*(NPB+1) (0.4 MB)
    unsigned int*   bmem  = (unsigned int*)(gsoff + (size_t)NBKT * (NPB + 1)); // 8 MB

    hipMemsetAsync(bcnt, 0, NBKT * sizeof(int), stream);

    int nblk = 2 * ((NBLK_B > NBLK_K1) ? NBLK_B : NBLK_K1);  // 782, roles interleaved
    k_fused<<<nblk, 256, 0, stream>>>(x, Wl1, Wr1, p, r, ei, As, ws, bcnt, bmem);
    k_agg1<<<NBKT, 256, 0, stream>>>(bcnt, bmem, p, r, bl1, Wl2, bl2, Wr2, q, out, gsoff);
    k_agg2<<<(NN + 255) / 256, 256, 0, stream>>>(gsoff, bmem, q, out);
}